// Round 3
// baseline (322.613 us; speedup 1.0000x reference)
//
#include <hip/hip_runtime.h>
#include <math.h>

#define BB 8192
#define DIN 1024
#define DZ 256
#define DH 256
#define DT 16
#define DREC 256

// d_out layout (floats): I_hat, z, h, z_hat, spatial, temporal, energy
#define OFF_IHAT 0
#define OFF_Z    (BB * DIN)
#define OFF_H    (OFF_Z + BB * DZ)
#define OFF_ZHAT (OFF_H + BB * DH)
#define OFF_SCAL (OFF_ZHAT + BB * DZ)

// workspace (u16 element offsets)
#define WS_SIGMA 0
#define WS_ZBF   2097152
#define WS_R1    4194304

#define LDA 72  // padded LDS row stride in u16 (2-way bank alias only = free)

typedef unsigned short u16;
typedef __attribute__((ext_vector_type(8))) unsigned short u16x8;
typedef __attribute__((ext_vector_type(8))) __bf16 bf16x8;
typedef __attribute__((ext_vector_type(4))) float f32x4;

__device__ inline u16 f2bf(float f) {
  unsigned u = __builtin_bit_cast(unsigned, f);
  u += 0x7fff + ((u >> 16) & 1);
  return (u16)(u >> 16);
}

__device__ inline float softplus_stable(float y) {  // log(1+e^y)
  return (y > 20.f) ? y : log1pf(expf(y));
}

__device__ inline float block_sum256(float v, float* rbuf) {
#pragma unroll
  for (int off = 32; off > 0; off >>= 1) v += __shfl_down(v, off, 64);
  __syncthreads();
  if ((threadIdx.x & 63) == 0) rbuf[threadIdx.x >> 6] = v;
  __syncthreads();
  return rbuf[0] + rbuf[1] + rbuf[2] + rbuf[3];
}

// ---- LDS staging helpers (256 threads), fp32 global -> bf16 LDS -----------
__device__ inline void stage64(u16* lds, const float* __restrict__ src,
                               int row0, int ld, int k0, float scale) {
  const int tid = threadIdx.x;
#pragma unroll
  for (int i = 0; i < 2; ++i) {
    int idx = tid + 256 * i;
    int r = idx >> 3, kc = idx & 7;
    const float* p = src + (size_t)(row0 + r) * ld + k0 + kc * 8;
    float4 v0 = *(const float4*)p;
    float4 v1 = *(const float4*)(p + 4);
    float vals[8] = {v0.x, v0.y, v0.z, v0.w, v1.x, v1.y, v1.z, v1.w};
    u16x8 o;
#pragma unroll
    for (int j = 0; j < 8; ++j) o[j] = f2bf(vals[j] * scale);
    *(u16x8*)(lds + r * LDA + kc * 8) = o;
  }
}

__device__ inline void stage64_bf(u16* lds, const u16* __restrict__ src,
                                  int row0, int ld, int k0) {
  const int tid = threadIdx.x;
#pragma unroll
  for (int i = 0; i < 2; ++i) {
    int idx = tid + 256 * i;
    int r = idx >> 3, kc = idx & 7;
    *(u16x8*)(lds + r * LDA + kc * 8) =
        *(const u16x8*)(src + (size_t)(row0 + r) * ld + k0 + kc * 8);
  }
}

// 16-row tile (theta B matrices), optional -relu transform
__device__ inline void stage16(u16* lds, const float* __restrict__ src, int ld,
                               int k0, float scale, bool nrelu) {
  const int tid = threadIdx.x;
  if (tid < 128) {
    int r = tid >> 3, kc = tid & 7;
    const float* p = src + (size_t)r * ld + k0 + kc * 8;
    float4 v0 = *(const float4*)p;
    float4 v1 = *(const float4*)(p + 4);
    float vals[8] = {v0.x, v0.y, v0.z, v0.w, v1.x, v1.y, v1.z, v1.w};
    u16x8 o;
#pragma unroll
    for (int j = 0; j < 8; ++j) {
      float x = vals[j];
      x = nrelu ? -fmaxf(x, 0.f) : x * scale;
      o[j] = f2bf(x);
    }
    *(u16x8*)(lds + r * LDA + kc * 8) = o;
  }
}

__device__ inline bf16x8 frag(const u16* lds, int row, int off) {
  return __builtin_bit_cast(bf16x8, *(const u16x8*)(lds + row * LDA + off));
}

#define MFMA __builtin_amdgcn_mfma_f32_16x16x32_bf16

// ---------------------------------------------------------------------------
// k_hp: h = relu(zm1@Wz2h^T + h@Wh2h^T); sigma_p = softplus_b(h@Wprl^T);
//       z_hat = relu(h@Wprm^T) + eps_zhat*sigma_p ; sigma -> bf16 ws.
// 64x64 tile, grid (4,128) = 512 blocks.
// ---------------------------------------------------------------------------
__global__ __launch_bounds__(256) void k_hp(
    const float* __restrict__ h_m_1, const float* __restrict__ z_m_1,
    const float* __restrict__ Wh2h, const float* __restrict__ Wprm,
    const float* __restrict__ Wprl, const float* __restrict__ Wz2h,
    const float* __restrict__ eps_zhat, float* __restrict__ h_out,
    float* __restrict__ zhat_out, u16* __restrict__ sigma_bf) {
  __shared__ __align__(16) u16 As[64 * LDA], B0s[64 * LDA], B1s[64 * LDA],
      B2s[64 * LDA];
  const int col0 = blockIdx.x * 64, row0 = blockIdx.y * 64;
  const int tid = threadIdx.x, lane = tid & 63, w = tid >> 6;
  const int frow = lane & 15, fq = lane >> 4;
  f32x4 acch[4], accm[4], accs[4];
#pragma unroll
  for (int ni = 0; ni < 4; ++ni) {
    acch[ni] = (f32x4){0.f, 0.f, 0.f, 0.f};
    accm[ni] = (f32x4){0.f, 0.f, 0.f, 0.f};
    accs[ni] = (f32x4){0.f, 0.f, 0.f, 0.f};
  }
  // pass 1: A = h_m_1, three B's (K = DH)
  for (int k0 = 0; k0 < DH; k0 += 64) {
    __syncthreads();
    stage64(As, h_m_1, row0, DH, k0, 1.f);
    stage64(B0s, Wh2h, col0, DH, k0, 1.f);
    stage64(B1s, Wprm, col0, DH, k0, 1.f);
    stage64(B2s, Wprl, col0, DH, k0, 1.f);
    __syncthreads();
#pragma unroll
    for (int ks = 0; ks < 2; ++ks) {
      int off = ks * 32 + fq * 8;
      bf16x8 a = frag(As, w * 16 + frow, off);
#pragma unroll
      for (int ni = 0; ni < 4; ++ni) {
        acch[ni] = MFMA(a, frag(B0s, ni * 16 + frow, off), acch[ni], 0, 0, 0);
        accm[ni] = MFMA(a, frag(B1s, ni * 16 + frow, off), accm[ni], 0, 0, 0);
        accs[ni] = MFMA(a, frag(B2s, ni * 16 + frow, off), accs[ni], 0, 0, 0);
      }
    }
  }
  // pass 2: A = z_m_1, B = Wz2h (K = DZ) accumulating into acch
  for (int k0 = 0; k0 < DZ; k0 += 64) {
    __syncthreads();
    stage64(As, z_m_1, row0, DZ, k0, 1.f);
    stage64(B0s, Wz2h, col0, DZ, k0, 1.f);
    __syncthreads();
#pragma unroll
    for (int ks = 0; ks < 2; ++ks) {
      int off = ks * 32 + fq * 8;
      bf16x8 a = frag(As, w * 16 + frow, off);
#pragma unroll
      for (int ni = 0; ni < 4; ++ni)
        acch[ni] = MFMA(a, frag(B0s, ni * 16 + frow, off), acch[ni], 0, 0, 0);
    }
  }
#pragma unroll
  for (int ni = 0; ni < 4; ++ni)
#pragma unroll
    for (int r = 0; r < 4; ++r) {
      int m = row0 + w * 16 + fq * 4 + r;
      int n = col0 + ni * 16 + frow;
      h_out[(size_t)m * DH + n] = fmaxf(acch[ni][r], 0.f);
      float sig = softplus_stable(1.2f * accs[ni][r]) * (1.f / 1.2f);
      float mu = fmaxf(accm[ni][r], 0.f);
      zhat_out[(size_t)m * DZ + n] = mu + eps_zhat[(size_t)m * DZ + n] * sig;
      sigma_bf[(size_t)m * DZ + n] = f2bf(sig);
    }
}

// ---------------------------------------------------------------------------
// k_post: mu_q/sigma_q dual GEMM (K=1024) with theta GEMM riding the same
// A tiles, + sigma@(-relu(Wv)) phase, + fused z epilogue and losses.
// 64x64 tile, grid (4,128) = 512 blocks.
// ---------------------------------------------------------------------------
__global__ __launch_bounds__(256) void k_post(
    const float* __restrict__ I_t, const float* __restrict__ Wpm,
    const float* __restrict__ Wpl, const float* __restrict__ Wi2t,
    const float* __restrict__ Wv, const u16* __restrict__ sigma_bf,
    const float* __restrict__ theta_m_1, const float* __restrict__ W_t2z,
    const float* __restrict__ eps_z, const float* __restrict__ zhat,
    float* __restrict__ z_out, u16* __restrict__ z_bf,
    float* __restrict__ scal) {
  __shared__ __align__(16) u16 As[64 * LDA], B0s[64 * LDA], B1s[64 * LDA],
      Bts[16 * LDA];
  __shared__ float rbuf[4];
  const int col0 = blockIdx.x * 64, row0 = blockIdx.y * 64;
  const int tid = threadIdx.x, lane = tid & 63, w = tid >> 6;
  const int frow = lane & 15, fq = lane >> 4;
  f32x4 accm[4], accs[4];
  f32x4 acct = (f32x4){0.f, 0.f, 0.f, 0.f};
#pragma unroll
  for (int ni = 0; ni < 4; ++ni) {
    accm[ni] = (f32x4){0.f, 0.f, 0.f, 0.f};
    accs[ni] = (f32x4){0.f, 0.f, 0.f, 0.f};
  }
  // main loop over I (K = DIN): mu, sigma, theta(I-part, 0.1 folded)
  for (int k0 = 0; k0 < DIN; k0 += 64) {
    __syncthreads();
    stage64(As, I_t, row0, DIN, k0, 1.f);
    stage64(B0s, Wpm, col0, DIN, k0, 1.f);
    stage64(B1s, Wpl, col0, DIN, k0, 1.f);
    stage16(Bts, Wi2t, DIN, k0, 0.1f, false);
    __syncthreads();
#pragma unroll
    for (int ks = 0; ks < 2; ++ks) {
      int off = ks * 32 + fq * 8;
      bf16x8 a = frag(As, w * 16 + frow, off);
#pragma unroll
      for (int ni = 0; ni < 4; ++ni) {
        accm[ni] = MFMA(a, frag(B0s, ni * 16 + frow, off), accm[ni], 0, 0, 0);
        accs[ni] = MFMA(a, frag(B1s, ni * 16 + frow, off), accs[ni], 0, 0, 0);
      }
      acct = MFMA(a, frag(Bts, frow, off), acct, 0, 0, 0);
    }
  }
  // theta sigma-part: acct += sigma @ (-relu(Wv))^T  (K = DZ)
  for (int k0 = 0; k0 < DZ; k0 += 64) {
    __syncthreads();
    stage64_bf(As, sigma_bf, row0, DZ, k0);
    stage16(Bts, Wv, DZ, k0, 1.f, true);
    __syncthreads();
#pragma unroll
    for (int ks = 0; ks < 2; ++ks) {
      int off = ks * 32 + fq * 8;
      acct = MFMA(frag(As, w * 16 + frow, off), frag(Bts, frow, off), acct, 0,
                  0, 0);
    }
  }
  // finalize theta for this block's 64 rows, broadcast via LDS
  __syncthreads();
  float* th_s = (float*)As;   // 64*17 floats
  float* wt_s = (float*)B0s;  // 64*17 floats
#pragma unroll
  for (int r = 0; r < 4; ++r) {
    int lr = w * 16 + fq * 4 + r;
    float th = 0.5f * theta_m_1[(size_t)(row0 + lr) * DT + frow] + acct[r];
    th_s[lr * 17 + frow] = 0.002f * softplus_stable(0.5f * th);
  }
  for (int idx = tid; idx < 64 * 16; idx += 256) {
    int n = idx >> 4, j = idx & 15;
    wt_s[n * 17 + j] = 10.f * fmaxf(W_t2z[(col0 + n) * DT + j], 0.f);
  }
  __syncthreads();
  // z epilogue + temporal/energy reductions
  float tsum = 0.f, esum = 0.f;
#pragma unroll
  for (int ni = 0; ni < 4; ++ni)
#pragma unroll
    for (int r = 0; r < 4; ++r) {
      int lr = w * 16 + fq * 4 + r;
      int ln = ni * 16 + frow;
      int m = row0 + lr;
      int n = col0 + ln;
      float mu = fmaxf(accm[ni][r], 0.f);
      float sq = fmaxf(accs[ni][r], 0.f);
      float raw = mu + eps_z[(size_t)m * DZ + n] * sq;
      raw = fminf(fmaxf(raw, 0.f), 1.f);
      float thr = 0.f;
#pragma unroll
      for (int j = 0; j < 16; ++j)
        thr = fmaf(th_s[lr * 17 + j], wt_s[ln * 17 + j], thr);
      float zz = fmaxf(raw - thr, 0.f);
      z_out[(size_t)m * DZ + n] = zz;
      z_bf[(size_t)m * DZ + n] = f2bf(zz);
      float d = zz - zhat[(size_t)m * DZ + n];
      tsum += d * d;
      esum += zz;
    }
  float t = block_sum256(tsum, rbuf);
  if (tid == 0) atomicAdd(scal + 1, t * (1.f / ((float)BB * DZ)));
  float e = block_sum256(esum, rbuf);
  if (tid == 0) atomicAdd(scal + 2, e * (1.f / ((float)BB * DZ)));
}

// ---------------------------------------------------------------------------
// k_rec1: r1 = z @ W_rec1^T -> bf16 ws.  64x64 tile, grid (4,128).
// ---------------------------------------------------------------------------
__global__ __launch_bounds__(256) void k_rec1(const u16* __restrict__ z_bf,
                                              const float* __restrict__ Wr1,
                                              u16* __restrict__ r1_bf) {
  __shared__ __align__(16) u16 As[64 * LDA], B0s[64 * LDA];
  const int col0 = blockIdx.x * 64, row0 = blockIdx.y * 64;
  const int tid = threadIdx.x, lane = tid & 63, w = tid >> 6;
  const int frow = lane & 15, fq = lane >> 4;
  f32x4 acc[4];
#pragma unroll
  for (int ni = 0; ni < 4; ++ni) acc[ni] = (f32x4){0.f, 0.f, 0.f, 0.f};
  for (int k0 = 0; k0 < DZ; k0 += 64) {
    __syncthreads();
    stage64_bf(As, z_bf, row0, DZ, k0);
    stage64(B0s, Wr1, col0, DZ, k0, 1.f);
    __syncthreads();
#pragma unroll
    for (int ks = 0; ks < 2; ++ks) {
      int off = ks * 32 + fq * 8;
      bf16x8 a = frag(As, w * 16 + frow, off);
#pragma unroll
      for (int ni = 0; ni < 4; ++ni)
        acc[ni] = MFMA(a, frag(B0s, ni * 16 + frow, off), acc[ni], 0, 0, 0);
    }
  }
#pragma unroll
  for (int ni = 0; ni < 4; ++ni)
#pragma unroll
    for (int r = 0; r < 4; ++r) {
      int m = row0 + w * 16 + fq * 4 + r;
      int n = col0 + ni * 16 + frow;
      r1_bf[(size_t)m * DREC + n] = f2bf(acc[ni][r]);
    }
}

// ---------------------------------------------------------------------------
// k_rec2: I_hat = sigmoid(r1 @ W_rec2^T) + fused spatial loss.
// 64x64 tile, grid (16,128) = 2048 blocks.
// ---------------------------------------------------------------------------
__global__ __launch_bounds__(256) void k_rec2(const u16* __restrict__ r1_bf,
                                              const float* __restrict__ Wr2,
                                              const float* __restrict__ I_t,
                                              float* __restrict__ ihat_out,
                                              float* __restrict__ scal) {
  __shared__ __align__(16) u16 As[64 * LDA], B0s[64 * LDA];
  __shared__ float rbuf[4];
  const int col0 = blockIdx.x * 64, row0 = blockIdx.y * 64;
  const int tid = threadIdx.x, lane = tid & 63, w = tid >> 6;
  const int frow = lane & 15, fq = lane >> 4;
  f32x4 acc[4];
#pragma unroll
  for (int ni = 0; ni < 4; ++ni) acc[ni] = (f32x4){0.f, 0.f, 0.f, 0.f};
  for (int k0 = 0; k0 < DREC; k0 += 64) {
    __syncthreads();
    stage64_bf(As, r1_bf, row0, DREC, k0);
    stage64(B0s, Wr2, col0, DREC, k0, 1.f);
    __syncthreads();
#pragma unroll
    for (int ks = 0; ks < 2; ++ks) {
      int off = ks * 32 + fq * 8;
      bf16x8 a = frag(As, w * 16 + frow, off);
#pragma unroll
      for (int ni = 0; ni < 4; ++ni)
        acc[ni] = MFMA(a, frag(B0s, ni * 16 + frow, off), acc[ni], 0, 0, 0);
    }
  }
  float lsum = 0.f;
#pragma unroll
  for (int ni = 0; ni < 4; ++ni)
#pragma unroll
    for (int r = 0; r < 4; ++r) {
      int m = row0 + w * 16 + fq * 4 + r;
      int n = col0 + ni * 16 + frow;
      float ih = 1.f / (1.f + expf(-acc[ni][r]));
      ihat_out[(size_t)m * DIN + n] = ih;
      float d = I_t[(size_t)m * DIN + n] - ih;
      lsum += d * d;
    }
  float s = block_sum256(lsum, rbuf);
  if (tid == 0) atomicAdd(scal + 0, s * (1.f / ((float)BB * DIN)));
}

// ---------------------------------------------------------------------------
extern "C" void kernel_launch(void* const* d_in, const int* in_sizes, int n_in,
                              void* d_out, int out_size, void* d_ws,
                              size_t ws_size, hipStream_t stream) {
  const float* I_t       = (const float*)d_in[0];
  const float* h_m_1     = (const float*)d_in[1];
  const float* z_m_1     = (const float*)d_in[2];
  const float* theta_m_1 = (const float*)d_in[3];
  const float* eps_z     = (const float*)d_in[4];
  const float* eps_zhat  = (const float*)d_in[5];
  const float* W_post_mu = (const float*)d_in[6];
  const float* W_post_lv = (const float*)d_in[7];
  const float* W_z2h     = (const float*)d_in[8];
  const float* W_h2h     = (const float*)d_in[9];
  const float* W_prior_mu= (const float*)d_in[10];
  const float* W_prior_lv= (const float*)d_in[11];
  const float* W_i2t     = (const float*)d_in[12];
  const float* W_vip2t   = (const float*)d_in[13];
  const float* W_t2z     = (const float*)d_in[14];
  const float* W_rec1    = (const float*)d_in[15];
  const float* W_rec2    = (const float*)d_in[16];

  float* out = (float*)d_out;
  float* ihat = out + OFF_IHAT;
  float* zout = out + OFF_Z;
  float* hout = out + OFF_H;
  float* zhat = out + OFF_ZHAT;
  float* scal = out + OFF_SCAL;

  u16* ws_u = (u16*)d_ws;
  u16* sigma_bf = ws_u + WS_SIGMA;
  u16* z_bf = ws_u + WS_ZBF;
  u16* r1_bf = ws_u + WS_R1;

  hipMemsetAsync(scal, 0, 3 * sizeof(float), stream);

  dim3 gz(DZ / 64, BB / 64);    // 4 x 128 = 512 blocks
  dim3 gi(DIN / 64, BB / 64);   // 16 x 128 = 2048 blocks

  k_hp<<<gz, 256, 0, stream>>>(h_m_1, z_m_1, W_h2h, W_prior_mu, W_prior_lv,
                               W_z2h, eps_zhat, hout, zhat, sigma_bf);
  k_post<<<gz, 256, 0, stream>>>(I_t, W_post_mu, W_post_lv, W_i2t, W_vip2t,
                                 sigma_bf, theta_m_1, W_t2z, eps_z, zhat, zout,
                                 z_bf, scal);
  k_rec1<<<gz, 256, 0, stream>>>(z_bf, W_rec1, r1_bf);
  k_rec2<<<gi, 256, 0, stream>>>(r1_bf, W_rec2, I_t, ihat, scal);
}